// Round 1
// baseline (239.129 us; speedup 1.0000x reference)
//
#include <hip/hip_runtime.h>
#include <math.h>

// Problem constants (from reference setup_inputs)
constexpr int B = 16;
constexpr int S = 4096;
constexpr int F = 512;
constexpr int L = 256;      // output s-positions per thread (per block chunk)
constexpr int BLOCK = 256;  // threads per block; each thread owns one f

// out[b,t,f] = sum_i softmax(w)[i]/k_i * sum_{d=-p_i}^{p_i} x[b, clamp(t+d), f]
// Implemented via local prefix sums: P[s] = sum of clamped x up to s (local base),
// window sum = P[t+p] - P[t-p-1]. Clamped reads == replicate padding exactly.
__global__ __launch_bounds__(BLOCK) void msavg_kernel(
    const float* __restrict__ x, const float* __restrict__ kw,
    float* __restrict__ out) {
  const int f  = blockIdx.x * BLOCK + threadIdx.x;   // 0..511
  const int t0 = blockIdx.y * L;                      // chunk start along S
  const int b  = blockIdx.z;

  // softmax over the 4 scale weights, folded with 1/k
  float w0 = kw[0], w1 = kw[1], w2 = kw[2], w3 = kw[3];
  float m  = fmaxf(fmaxf(w0, w1), fmaxf(w2, w3));
  float e0 = expf(w0 - m), e1 = expf(w1 - m), e2 = expf(w2 - m), e3 = expf(w3 - m);
  float inv = 1.0f / (e0 + e1 + e2 + e3);
  const float c3  = e0 * inv * (1.0f / 3.0f);
  const float c7  = e1 * inv * (1.0f / 7.0f);
  const float c15 = e2 * inv * (1.0f / 15.0f);
  const float c31 = e3 * inv * (1.0f / 31.0f);

  const float* xb = x   + ((size_t)b * S) * F + f;
  float*       ob = out + ((size_t)b * S) * F + f;

  // prev[i] = P[t0 - 16 + i]   (i = 0..31)
  // cur[i]  = P[T  + 16 + i]   for the current output group starting at T
  float prev[32], cur[32];

  {
    float p = 0.0f;
#pragma unroll
    for (int j = 0; j < 32; ++j) {
      int s = t0 - 16 + j;
      s = s < 0 ? 0 : (s > S - 1 ? S - 1 : s);
      p += xb[(size_t)s * F];
      prev[j] = p;
    }
  }

#pragma unroll 2
  for (int g = 0; g < L / 32; ++g) {
    const int T = t0 + g * 32;

    // Load the next 32 inputs (s = T+16 .. T+47), clamped at the right edge.
    float xv[32];
    if (T + 47 <= S - 1) {
#pragma unroll
      for (int j = 0; j < 32; ++j) xv[j] = xb[(size_t)(T + 16 + j) * F];
    } else {
#pragma unroll
      for (int j = 0; j < 32; ++j) {
        int s = T + 16 + j;
        s = s > S - 1 ? S - 1 : s;
        xv[j] = xb[(size_t)s * F];
      }
    }

    // Extend the prefix: cur[j] = P[T+16+j]
    {
      float p = prev[31];
#pragma unroll
      for (int j = 0; j < 32; ++j) {
        p += xv[j];
        cur[j] = p;
      }
    }

    // Emit 32 outputs t = T + j. prev covers P[T-16..T+15], cur covers P[T+16..T+47].
#pragma unroll
    for (int j = 0; j < 32; ++j) {
      float Pp15 = (j < 1)  ? prev[j + 31] : cur[j - 1];
      float Pp7  = (j < 9)  ? prev[j + 23] : cur[j - 9];
      float Pp3  = (j < 13) ? prev[j + 19] : cur[j - 13];
      float Pp1  = (j < 15) ? prev[j + 17] : cur[j - 15];
      float Pm2  = (j < 18) ? prev[j + 14] : cur[j - 18];
      float Pm4  = (j < 20) ? prev[j + 12] : cur[j - 20];
      float Pm8  = (j < 24) ? prev[j + 8]  : cur[j - 24];
      float Pm16 = prev[j];
      float o = c3  * (Pp1  - Pm2) +
                c7  * (Pp3  - Pm4) +
                c15 * (Pp7  - Pm8) +
                c31 * (Pp15 - Pm16);
      ob[(size_t)(T + j) * F] = o;
    }

    // Roll the window
#pragma unroll
    for (int j = 0; j < 32; ++j) prev[j] = cur[j];
  }
}

extern "C" void kernel_launch(void* const* d_in, const int* in_sizes, int n_in,
                              void* d_out, int out_size, void* d_ws, size_t ws_size,
                              hipStream_t stream) {
  const float* x  = (const float*)d_in[0];  // [16, 4096, 512] fp32
  const float* kw = (const float*)d_in[1];  // [4] fp32
  float* out = (float*)d_out;               // [16, 4096, 512] fp32
  (void)in_sizes; (void)n_in; (void)out_size; (void)d_ws; (void)ws_size;

  dim3 grid(F / BLOCK, S / L, B);  // (2, 16, 16) = 512 blocks
  msavg_kernel<<<grid, BLOCK, 0, stream>>>(x, kw, out);
}

// Round 2
// 237.962 us; speedup vs baseline: 1.0049x; 1.0049x over previous
//
#include <hip/hip_runtime.h>
#include <math.h>

// Problem constants (from reference setup_inputs)
constexpr int B = 16;
constexpr int S = 4096;
constexpr int F = 512;
constexpr int L = 64;       // output s-positions per thread (per block chunk)
                            // L=64 -> grid 2048 blocks -> 8192 waves -> 8 waves/SIMD (full occupancy @60 VGPR)
constexpr int BLOCK = 256;  // threads per block; each thread owns one f

// out[b,t,f] = sum_i softmax(w)[i]/k_i * sum_{d=-p_i}^{p_i} x[b, clamp(t+d), f]
// Implemented via local prefix sums: P[s] = sum of clamped x up to s (local base),
// window sum = P[t+p] - P[t-p-1]. Clamped reads == replicate padding exactly.
__global__ __launch_bounds__(BLOCK) void msavg_kernel(
    const float* __restrict__ x, const float* __restrict__ kw,
    float* __restrict__ out) {
  const int f  = blockIdx.x * BLOCK + threadIdx.x;   // 0..511
  const int t0 = blockIdx.y * L;                      // chunk start along S
  const int b  = blockIdx.z;

  // softmax over the 4 scale weights, folded with 1/k (uniform -> scalar regs)
  float w0 = kw[0], w1 = kw[1], w2 = kw[2], w3 = kw[3];
  float m  = fmaxf(fmaxf(w0, w1), fmaxf(w2, w3));
  float e0 = expf(w0 - m), e1 = expf(w1 - m), e2 = expf(w2 - m), e3 = expf(w3 - m);
  float inv = 1.0f / (e0 + e1 + e2 + e3);
  const float c3  = e0 * inv * (1.0f / 3.0f);
  const float c7  = e1 * inv * (1.0f / 7.0f);
  const float c15 = e2 * inv * (1.0f / 15.0f);
  const float c31 = e3 * inv * (1.0f / 31.0f);

  const float* xb = x   + ((size_t)b * S) * F + f;
  float*       ob = out + ((size_t)b * S) * F + f;

  // prev[i] = P[t0 - 16 + i]   (i = 0..31)
  // cur[i]  = P[T  + 16 + i]   for the current output group starting at T
  float prev[32], cur[32];

  {
    float p = 0.0f;
#pragma unroll
    for (int j = 0; j < 32; ++j) {
      int s = t0 - 16 + j;
      s = s < 0 ? 0 : (s > S - 1 ? S - 1 : s);
      p += xb[(size_t)s * F];
      prev[j] = p;
    }
  }

#pragma unroll
  for (int g = 0; g < L / 32; ++g) {
    const int T = t0 + g * 32;

    // Load the next 32 inputs (s = T+16 .. T+47), clamped at the right edge.
    float xv[32];
    if (T + 47 <= S - 1) {
#pragma unroll
      for (int j = 0; j < 32; ++j) xv[j] = xb[(size_t)(T + 16 + j) * F];
    } else {
#pragma unroll
      for (int j = 0; j < 32; ++j) {
        int s = T + 16 + j;
        s = s > S - 1 ? S - 1 : s;
        xv[j] = xb[(size_t)s * F];
      }
    }

    // Extend the prefix: cur[j] = P[T+16+j]
    {
      float p = prev[31];
#pragma unroll
      for (int j = 0; j < 32; ++j) {
        p += xv[j];
        cur[j] = p;
      }
    }

    // Emit 32 outputs t = T + j. prev covers P[T-16..T+15], cur covers P[T+16..T+47].
#pragma unroll
    for (int j = 0; j < 32; ++j) {
      float Pp15 = (j < 1)  ? prev[j + 31] : cur[j - 1];
      float Pp7  = (j < 9)  ? prev[j + 23] : cur[j - 9];
      float Pp3  = (j < 13) ? prev[j + 19] : cur[j - 13];
      float Pp1  = (j < 15) ? prev[j + 17] : cur[j - 15];
      float Pm2  = (j < 18) ? prev[j + 14] : cur[j - 18];
      float Pm4  = (j < 20) ? prev[j + 12] : cur[j - 20];
      float Pm8  = (j < 24) ? prev[j + 8]  : cur[j - 24];
      float Pm16 = prev[j];
      float o = c3  * (Pp1  - Pm2) +
                c7  * (Pp3  - Pm4) +
                c15 * (Pp7  - Pm8) +
                c31 * (Pp15 - Pm16);
      ob[(size_t)(T + j) * F] = o;
    }

    // Roll the window
#pragma unroll
    for (int j = 0; j < 32; ++j) prev[j] = cur[j];
  }
}

extern "C" void kernel_launch(void* const* d_in, const int* in_sizes, int n_in,
                              void* d_out, int out_size, void* d_ws, size_t ws_size,
                              hipStream_t stream) {
  const float* x  = (const float*)d_in[0];  // [16, 4096, 512] fp32
  const float* kw = (const float*)d_in[1];  // [4] fp32
  float* out = (float*)d_out;               // [16, 4096, 512] fp32
  (void)in_sizes; (void)n_in; (void)out_size; (void)d_ws; (void)ws_size;

  dim3 grid(F / BLOCK, S / L, B);  // (2, 64, 16) = 2048 blocks
  msavg_kernel<<<grid, BLOCK, 0, stream>>>(x, kw, out);
}